// Round 3
// baseline (634.875 us; speedup 1.0000x reference)
//
#include <hip/hip_runtime.h>
#include <hip/hip_bf16.h>

// Problem constants: V=128000, D=512, B=2, T=1024, K=512
#define V_SZ   128000
#define D_SZ   512
#define N_ROWS 2048
#define K_SZ   512
#define KM1    511
#define M_PAIRS (N_ROWS * K_SZ)   // 1,048,576 ; pair id = (n<<9)|k
#define NCHUNK  250               // V_SZ / 512

// ---------------- candidate index for pair gid ----------------
__device__ __forceinline__ int cand_of(int gid, const int* __restrict__ labels,
                                       const int* __restrict__ neg) {
    int n = gid >> 9, k = gid & 511;
    return (k == 0) ? labels[n] : neg[n * KM1 + (k - 1)];
}

// ---------------- pipeline kernels ----------------
__global__ void k_zero(int* __restrict__ counts, float* __restrict__ out) {
    int gid = blockIdx.x * 256 + threadIdx.x;
    if (gid < V_SZ) counts[gid] = 0;
    if (gid == 0) out[0] = 0.0f;
}

__global__ __launch_bounds__(256) void k_hist(const int* __restrict__ labels,
                                              const int* __restrict__ neg,
                                              int* __restrict__ counts) {
    int gid = blockIdx.x * 256 + threadIdx.x;   // grid covers M_PAIRS exactly
    atomicAdd(&counts[cand_of(gid, labels, neg)], 1);
}

__global__ __launch_bounds__(256) void k_chunk_sum(const int* __restrict__ counts,
                                                   int* __restrict__ partials) {
    int base = blockIdx.x * 512;
    int t = threadIdx.x;
    int s = counts[base + t] + counts[base + t + 256];
    #pragma unroll
    for (int off = 32; off > 0; off >>= 1) s += __shfl_xor(s, off);
    __shared__ int r[4];
    if ((t & 63) == 0) r[t >> 6] = s;
    __syncthreads();
    if (t == 0) partials[blockIdx.x] = r[0] + r[1] + r[2] + r[3];
}

__global__ __launch_bounds__(256) void k_scan_partials(int* __restrict__ partials) {
    int t = threadIdx.x;
    int x = (t < NCHUNK) ? partials[t] : 0;
    __shared__ int s[256];
    s[t] = x; __syncthreads();
    #pragma unroll
    for (int off = 1; off < 256; off <<= 1) {
        int v = (t >= off) ? s[t - off] : 0;
        __syncthreads();
        s[t] += v;
        __syncthreads();
    }
    if (t < NCHUNK) partials[t] = s[t] - x;   // exclusive base per chunk
}

__global__ __launch_bounds__(256) void k_scan_chunks(const int* __restrict__ counts,
                                                     const int* __restrict__ partials,
                                                     int* __restrict__ offsets,
                                                     int* __restrict__ cursor) {
    int b = blockIdx.x, t = threadIdx.x;
    int base = b * 512;
    int c0 = counts[base + 2 * t], c1 = counts[base + 2 * t + 1];
    int ps = c0 + c1;
    __shared__ int s[256];
    s[t] = ps; __syncthreads();
    #pragma unroll
    for (int off = 1; off < 256; off <<= 1) {
        int v = (t >= off) ? s[t - off] : 0;
        __syncthreads();
        s[t] += v;
        __syncthreads();
    }
    int excl = s[t] - ps;
    int o0 = partials[b] + excl;
    int o1 = o0 + c0;
    offsets[base + 2 * t]     = o0;  cursor[base + 2 * t]     = o0;
    offsets[base + 2 * t + 1] = o1;  cursor[base + 2 * t + 1] = o1;
    if (b == NCHUNK - 1 && t == 255) offsets[V_SZ] = o1 + c1;   // == M_PAIRS
}

__global__ __launch_bounds__(256) void k_scatter(const int* __restrict__ labels,
                                                 const int* __restrict__ neg,
                                                 int* __restrict__ cursor,
                                                 int* __restrict__ sorted) {
    int gid = blockIdx.x * 256 + threadIdx.x;
    int c = cand_of(gid, labels, neg);
    int pos = atomicAdd(&cursor[c], 1);
    sorted[pos] = gid;   // gid IS the packed (n<<9)|k
}

// One wave per vocab row: read W[c] once, gather H[n] per pair (H is L2-hot).
__global__ __launch_bounds__(256) void k_compute(const float* __restrict__ W,
                                                 const float* __restrict__ H,
                                                 const int* __restrict__ offsets,
                                                 const int* __restrict__ sorted,
                                                 float* __restrict__ Lmat) {
    const int lane = threadIdx.x & 63;
    const int c = blockIdx.x * 4 + (threadIdx.x >> 6);   // grid = V/4 blocks exactly
    const int begin = offsets[c], end = offsets[c + 1];
    if (begin == end) return;
    const float4* Wr = reinterpret_cast<const float4*>(W + (size_t)c * D_SZ);
    float4 w0 = Wr[lane], w1 = Wr[lane + 64];   // contiguous 1KB per instruction
    for (int pos = begin; pos < end; ++pos) {
        int packed = sorted[pos];
        const float4* Hr = reinterpret_cast<const float4*>(H + (size_t)(packed >> 9) * D_SZ);
        float4 h0 = Hr[lane], h1 = Hr[lane + 64];
        float s = 0.f;
        s = fmaf(w0.x, h0.x, s); s = fmaf(w0.y, h0.y, s);
        s = fmaf(w0.z, h0.z, s); s = fmaf(w0.w, h0.w, s);
        s = fmaf(w1.x, h1.x, s); s = fmaf(w1.y, h1.y, s);
        s = fmaf(w1.z, h1.z, s); s = fmaf(w1.w, h1.w, s);
        s += __shfl_xor(s, 32); s += __shfl_xor(s, 16); s += __shfl_xor(s, 8);
        s += __shfl_xor(s, 4);  s += __shfl_xor(s, 2);  s += __shfl_xor(s, 1);
        if (lane == 0) Lmat[packed] = s;
    }
}

__global__ __launch_bounds__(256) void k_lse(const float* __restrict__ Lmat,
                                             const int* __restrict__ labels,
                                             const float* __restrict__ q,
                                             float* __restrict__ out) {
    const int n = blockIdx.x, t = threadIdx.x;
    const float* row = Lmat + (size_t)n * K_SZ;
    float a = row[t], b = row[t + 256];
    __shared__ float red[4];
    float m = fmaxf(a, b);
    #pragma unroll
    for (int off = 32; off > 0; off >>= 1) m = fmaxf(m, __shfl_xor(m, off));
    if ((t & 63) == 0) red[t >> 6] = m;
    __syncthreads();
    m = fmaxf(fmaxf(red[0], red[1]), fmaxf(red[2], red[3]));
    __syncthreads();
    float e = __expf(a - m) + __expf(b - m);
    #pragma unroll
    for (int off = 32; off > 0; off >>= 1) e += __shfl_xor(e, off);
    if ((t & 63) == 0) red[t >> 6] = e;
    __syncthreads();
    if (t == 0) {
        float tot = red[0] + red[1] + red[2] + red[3];
        float lse = m + logf(tot);
        float q0 = fmaxf(q[labels[n]], 1e-10f);
        float loss = -row[0] + lse + logf(q0);
        atomicAdd(out, loss * (1.0f / N_ROWS));
    }
}

// ---------------- fallback (round-2 monolithic kernel) ----------------
__global__ void zero_out_kernel(float* out) { out[0] = 0.0f; }

__global__ __launch_bounds__(256) void sampled_softmax_loss_kernel(
    const float* __restrict__ H, const int* __restrict__ labels,
    const float* __restrict__ W, const float* __restrict__ q,
    const int* __restrict__ neg, float* __restrict__ out)
{
    const int n = blockIdx.x, tid = threadIdx.x;
    const int sub = tid & 15, grp = tid >> 4;
    __shared__ int   cidx[K_SZ];
    __shared__ float logits[K_SZ];
    __shared__ float red[4];
    for (int i = tid; i < K_SZ; i += 256)
        cidx[i] = (i == 0) ? labels[n] : neg[(size_t)n * KM1 + (i - 1)];
    float4 h[8];
    const float4* Hrow = reinterpret_cast<const float4*>(H + (size_t)n * D_SZ);
    #pragma unroll
    for (int ch = 0; ch < 8; ++ch) h[ch] = Hrow[sub + ch * 16];
    __syncthreads();
    for (int base = grp; base < K_SZ; base += 16) {
        const float4* Wrow = reinterpret_cast<const float4*>(W + (size_t)cidx[base] * D_SZ);
        float4 acc = make_float4(0.f, 0.f, 0.f, 0.f);
        #pragma unroll
        for (int ch = 0; ch < 8; ++ch) {
            float4 w = Wrow[sub + ch * 16];
            acc.x = fmaf(w.x, h[ch].x, acc.x); acc.y = fmaf(w.y, h[ch].y, acc.y);
            acc.z = fmaf(w.z, h[ch].z, acc.z); acc.w = fmaf(w.w, h[ch].w, acc.w);
        }
        float s = (acc.x + acc.y) + (acc.z + acc.w);
        s += __shfl_xor(s, 1); s += __shfl_xor(s, 2);
        s += __shfl_xor(s, 4); s += __shfl_xor(s, 8);
        if (sub == 0) logits[base] = s;
    }
    __syncthreads();
    const int wave = tid >> 6;
    float m = -INFINITY;
    for (int i = tid; i < K_SZ; i += 256) m = fmaxf(m, logits[i]);
    #pragma unroll
    for (int off = 32; off > 0; off >>= 1) m = fmaxf(m, __shfl_xor(m, off));
    if ((tid & 63) == 0) red[wave] = m;
    __syncthreads();
    m = fmaxf(fmaxf(red[0], red[1]), fmaxf(red[2], red[3]));
    __syncthreads();
    float s = 0.f;
    for (int i = tid; i < K_SZ; i += 256) s += expf(logits[i] - m);
    #pragma unroll
    for (int off = 32; off > 0; off >>= 1) s += __shfl_xor(s, off);
    if ((tid & 63) == 0) red[wave] = s;
    __syncthreads();
    if (tid == 0) {
        float tot = red[0] + red[1] + red[2] + red[3];
        float lse = m + logf(tot);
        float q0 = fmaxf(q[cidx[0]], 1e-10f);
        atomicAdd(out, (-logits[0] + lse + logf(q0)) * (1.0f / N_ROWS));
    }
}

// ---------------- launch ----------------
extern "C" void kernel_launch(void* const* d_in, const int* in_sizes, int n_in,
                              void* d_out, int out_size, void* d_ws, size_t ws_size,
                              hipStream_t stream) {
    const float* H      = (const float*)d_in[0];
    const int*   labels = (const int*)  d_in[1];
    const float* W      = (const float*)d_in[2];
    const float* q      = (const float*)d_in[3];
    const int*   neg    = (const int*)  d_in[4];
    float* out = (float*)d_out;

    // ws carve-up (all int32/fp32, 4B aligned; base is allocation-aligned)
    const size_t needed = (size_t)(V_SZ            // counts
                                 + V_SZ + 1        // offsets
                                 + V_SZ            // cursor
                                 + 256             // partials
                                 + M_PAIRS         // sorted
                                 + M_PAIRS) * 4;   // Lmat
    if (ws_size < needed) {   // safety fallback: round-2 kernel
        zero_out_kernel<<<1, 1, 0, stream>>>(out);
        sampled_softmax_loss_kernel<<<N_ROWS, 256, 0, stream>>>(H, labels, W, q, neg, out);
        return;
    }

    int* counts   = (int*)d_ws;
    int* offsets  = counts + V_SZ;
    int* cursor   = offsets + (V_SZ + 1);
    int* partials = cursor + V_SZ;
    int* sorted   = partials + 256;
    float* Lmat   = (float*)(sorted + M_PAIRS);

    k_zero         <<<512, 256, 0, stream>>>(counts, out);
    k_hist         <<<M_PAIRS / 256, 256, 0, stream>>>(labels, neg, counts);
    k_chunk_sum    <<<NCHUNK, 256, 0, stream>>>(counts, partials);
    k_scan_partials<<<1, 256, 0, stream>>>(partials);
    k_scan_chunks  <<<NCHUNK, 256, 0, stream>>>(counts, partials, offsets, cursor);
    k_scatter      <<<M_PAIRS / 256, 256, 0, stream>>>(labels, neg, cursor, sorted);
    k_compute      <<<V_SZ / 4, 256, 0, stream>>>(W, H, offsets, sorted, Lmat);
    k_lse          <<<N_ROWS, 256, 0, stream>>>(Lmat, labels, q, out);
}

// Round 4
// 521.551 us; speedup vs baseline: 1.2173x; 1.2173x over previous
//
#include <hip/hip_runtime.h>
#include <hip/hip_bf16.h>

// Problem constants: V=128000, D=512, B=2, T=1024, K=512
#define V_SZ   128000
#define D_SZ   512
#define N_ROWS 2048
#define K_SZ   512
#define KM1    511
#define W_ELEMS ((size_t)V_SZ * D_SZ)          // 65,536,000
#define W_VEC4  (W_ELEMS / 4)                  // 16,384,000 float4s

__device__ __forceinline__ float bl(unsigned u) {   // low bf16 of packed u32
    unsigned x = u << 16; return __uint_as_float(x);
}
__device__ __forceinline__ float bh(unsigned u) {   // high bf16
    unsigned x = u & 0xffff0000u; return __uint_as_float(x);
}

// ---------- W fp32 -> bf16 conversion into d_ws (also zeroes out[0]) ----------
__global__ __launch_bounds__(256) void k_convert(const float* __restrict__ W,
                                                 ushort* __restrict__ Wb,
                                                 float* __restrict__ out) {
    if (blockIdx.x == 0 && threadIdx.x == 0) out[0] = 0.0f;
    const size_t stride = (size_t)gridDim.x * 256;
    for (size_t i = (size_t)blockIdx.x * 256 + threadIdx.x; i < W_VEC4; i += stride) {
        float4 v = reinterpret_cast<const float4*>(W)[i];
        ushort4 b;
        b.x = __hip_bfloat16_raw(__float2bfloat16(v.x)).x;
        b.y = __hip_bfloat16_raw(__float2bfloat16(v.y)).x;
        b.z = __hip_bfloat16_raw(__float2bfloat16(v.z)).x;
        b.w = __hip_bfloat16_raw(__float2bfloat16(v.w)).x;
        reinterpret_cast<ushort4*>(Wb)[i] = b;
    }
}

// ---------- monolithic sampled-softmax with bf16 W gather ----------
__global__ __launch_bounds__(256) void k_main_bf16(
    const float* __restrict__ H, const int* __restrict__ labels,
    const ushort* __restrict__ Wb, const float* __restrict__ q,
    const int* __restrict__ neg, float* __restrict__ out)
{
    const int n   = blockIdx.x;
    const int tid = threadIdx.x;
    const int sub = tid & 15;   // lane in 16-lane candidate group
    const int grp = tid >> 4;

    __shared__ int   cidx[K_SZ];
    __shared__ float logits[K_SZ];
    __shared__ float red[4];

    for (int i = tid; i < K_SZ; i += 256)
        cidx[i] = (i == 0) ? labels[n] : neg[(size_t)n * KM1 + (i - 1)];

    // H chunks matching the bf16 W layout: chunk ch covers elements
    // [ch*128 + sub*8 .. +7]  -> two float4s at index ch*32 + sub*2
    const float4* Hr4 = reinterpret_cast<const float4*>(H + (size_t)n * D_SZ);
    float4 ha[4], hb[4];
    #pragma unroll
    for (int ch = 0; ch < 4; ++ch) {
        ha[ch] = Hr4[ch * 32 + sub * 2];
        hb[ch] = Hr4[ch * 32 + sub * 2 + 1];
    }
    __syncthreads();

    for (int base = grp; base < K_SZ; base += 16) {
        const int c = cidx[base];
        const uint4* Wr = reinterpret_cast<const uint4*>(Wb + (size_t)c * D_SZ);
        float s = 0.f;
        #pragma unroll
        for (int ch = 0; ch < 4; ++ch) {
            uint4 wv = Wr[ch * 16 + sub];        // 16B = 8 bf16, coalesced 256B/group
            s = fmaf(bl(wv.x), ha[ch].x, s); s = fmaf(bh(wv.x), ha[ch].y, s);
            s = fmaf(bl(wv.y), ha[ch].z, s); s = fmaf(bh(wv.y), ha[ch].w, s);
            s = fmaf(bl(wv.z), hb[ch].x, s); s = fmaf(bh(wv.z), hb[ch].y, s);
            s = fmaf(bl(wv.w), hb[ch].z, s); s = fmaf(bh(wv.w), hb[ch].w, s);
        }
        s += __shfl_xor(s, 1); s += __shfl_xor(s, 2);
        s += __shfl_xor(s, 4); s += __shfl_xor(s, 8);
        if (sub == 0) logits[base] = s;
    }
    __syncthreads();

    // logsumexp over the 512 logits
    const int wave = tid >> 6;
    float a = logits[tid], b2 = logits[tid + 256];
    float m = fmaxf(a, b2);
    #pragma unroll
    for (int off = 32; off > 0; off >>= 1) m = fmaxf(m, __shfl_xor(m, off));
    if ((tid & 63) == 0) red[wave] = m;
    __syncthreads();
    m = fmaxf(fmaxf(red[0], red[1]), fmaxf(red[2], red[3]));
    __syncthreads();
    float e = __expf(a - m) + __expf(b2 - m);
    #pragma unroll
    for (int off = 32; off > 0; off >>= 1) e += __shfl_xor(e, off);
    if ((tid & 63) == 0) red[wave] = e;
    __syncthreads();
    if (tid == 0) {
        float tot = red[0] + red[1] + red[2] + red[3];
        float lse = m + logf(tot);
        float q0  = fmaxf(q[cidx[0]], 1e-10f);
        atomicAdd(out, (-logits[0] + lse + logf(q0)) * (1.0f / N_ROWS));
    }
}

// ---------------- fallback (round-2 fp32 monolithic kernel) ----------------
__global__ void zero_out_kernel(float* out) { out[0] = 0.0f; }

__global__ __launch_bounds__(256) void sampled_softmax_loss_kernel(
    const float* __restrict__ H, const int* __restrict__ labels,
    const float* __restrict__ W, const float* __restrict__ q,
    const int* __restrict__ neg, float* __restrict__ out)
{
    const int n = blockIdx.x, tid = threadIdx.x;
    const int sub = tid & 15, grp = tid >> 4;
    __shared__ int   cidx[K_SZ];
    __shared__ float logits[K_SZ];
    __shared__ float red[4];
    for (int i = tid; i < K_SZ; i += 256)
        cidx[i] = (i == 0) ? labels[n] : neg[(size_t)n * KM1 + (i - 1)];
    float4 h[8];
    const float4* Hrow = reinterpret_cast<const float4*>(H + (size_t)n * D_SZ);
    #pragma unroll
    for (int ch = 0; ch < 8; ++ch) h[ch] = Hrow[sub + ch * 16];
    __syncthreads();
    for (int base = grp; base < K_SZ; base += 16) {
        const float4* Wrow = reinterpret_cast<const float4*>(W + (size_t)cidx[base] * D_SZ);
        float4 acc = make_float4(0.f, 0.f, 0.f, 0.f);
        #pragma unroll
        for (int ch = 0; ch < 8; ++ch) {
            float4 w = Wrow[sub + ch * 16];
            acc.x = fmaf(w.x, h[ch].x, acc.x); acc.y = fmaf(w.y, h[ch].y, acc.y);
            acc.z = fmaf(w.z, h[ch].z, acc.z); acc.w = fmaf(w.w, h[ch].w, acc.w);
        }
        float s = (acc.x + acc.y) + (acc.z + acc.w);
        s += __shfl_xor(s, 1); s += __shfl_xor(s, 2);
        s += __shfl_xor(s, 4); s += __shfl_xor(s, 8);
        if (sub == 0) logits[base] = s;
    }
    __syncthreads();
    const int wave = tid >> 6;
    float m = -INFINITY;
    for (int i = tid; i < K_SZ; i += 256) m = fmaxf(m, logits[i]);
    #pragma unroll
    for (int off = 32; off > 0; off >>= 1) m = fmaxf(m, __shfl_xor(m, off));
    if ((tid & 63) == 0) red[wave] = m;
    __syncthreads();
    m = fmaxf(fmaxf(red[0], red[1]), fmaxf(red[2], red[3]));
    __syncthreads();
    float s = 0.f;
    for (int i = tid; i < K_SZ; i += 256) s += expf(logits[i] - m);
    #pragma unroll
    for (int off = 32; off > 0; off >>= 1) s += __shfl_xor(s, off);
    if ((tid & 63) == 0) red[wave] = s;
    __syncthreads();
    if (tid == 0) {
        float tot = red[0] + red[1] + red[2] + red[3];
        float lse = m + logf(tot);
        float q0 = fmaxf(q[cidx[0]], 1e-10f);
        atomicAdd(out, (-logits[0] + lse + logf(q0)) * (1.0f / N_ROWS));
    }
}

// ---------------- launch ----------------
extern "C" void kernel_launch(void* const* d_in, const int* in_sizes, int n_in,
                              void* d_out, int out_size, void* d_ws, size_t ws_size,
                              hipStream_t stream) {
    const float* H      = (const float*)d_in[0];
    const int*   labels = (const int*)  d_in[1];
    const float* W      = (const float*)d_in[2];
    const float* q      = (const float*)d_in[3];
    const int*   neg    = (const int*)  d_in[4];
    float* out = (float*)d_out;

    const size_t need_bf16 = W_ELEMS * sizeof(ushort);   // 131,072,000 B
    if (ws_size >= need_bf16) {
        ushort* Wb = (ushort*)d_ws;
        k_convert  <<<2048, 256, 0, stream>>>(W, Wb, out);
        k_main_bf16<<<N_ROWS, 256, 0, stream>>>(H, labels, Wb, q, neg, out);
    } else {
        zero_out_kernel<<<1, 1, 0, stream>>>(out);
        sampled_softmax_loss_kernel<<<N_ROWS, 256, 0, stream>>>(H, labels, W, q, neg, out);
    }
}

// Round 7
// 443.359 us; speedup vs baseline: 1.4320x; 1.1764x over previous
//
#include <hip/hip_runtime.h>
#include <hip/hip_bf16.h>

// Problem constants: V=128000, D=512, B=2, T=1024, K=512
#define V_SZ   128000
#define D_SZ   512
#define N_ROWS 2048
#define K_SZ   512
#define KM1    511
#define W_ELEMS   ((size_t)V_SZ * D_SZ)     // 65,536,000
#define SCALE     64.0f
#define INV_SCALE (1.0f / 64.0f)

typedef float v2f __attribute__((ext_vector_type(2)));

#if defined(__has_builtin)
#if __has_builtin(__builtin_amdgcn_cvt_pk_f32_fp8) && __has_builtin(__builtin_amdgcn_cvt_pk_fp8_f32)
#define HW_FP8 1
#endif
#endif

// ---------- fp8 encode/decode (HW path; manual OCP-e4m3 bit-trick fallback) ----------
#ifdef HW_FP8
__device__ __forceinline__ unsigned pack4(float a, float b, float c, float d) {
    int u = 0;
    u = __builtin_amdgcn_cvt_pk_fp8_f32(a, b, u, false);  // bytes 0,1
    u = __builtin_amdgcn_cvt_pk_fp8_f32(c, d, u, true);   // bytes 2,3
    return (unsigned)u;
}
#define F8X2(u, hi) __builtin_amdgcn_cvt_pk_f32_fp8((int)(u), (hi))
#else
__device__ __forceinline__ unsigned enc1(float f) {
    unsigned b = __float_as_uint(f);
    unsigned sgn = (b >> 24) & 0x80u;
    unsigned mag = (b & 0x7fffffffu) + 0x00080000u;   // round at mantissa bit 20
    int e = (int)(mag >> 23) - 120;                   // e4m3 biased exponent
    unsigned m = (mag >> 20) & 7u;
    unsigned val = (e <= 0) ? 0u : ((e >= 16) ? 0x7eu : (((unsigned)e << 3) | m));
    return sgn | val;
}
__device__ __forceinline__ unsigned pack4(float a, float b, float c, float d) {
    return enc1(a) | (enc1(b) << 8) | (enc1(c) << 16) | (enc1(d) << 24);
}
__device__ __forceinline__ v2f f8x2m(unsigned u, int hi) {
    unsigned b0 = (u >> (hi ? 16 : 0)) & 0xffu;
    unsigned b1 = (u >> (hi ? 24 : 8)) & 0xffu;
    unsigned u0 = ((b0 & 0x7fu) << 20) + (120u << 23); u0 |= (b0 & 0x80u) << 24;
    unsigned u1 = ((b1 & 0x7fu) << 20) + (120u << 23); u1 |= (b1 & 0x80u) << 24;
    v2f r; r.x = __uint_as_float(u0); r.y = __uint_as_float(u1);
    return r;
}
#define F8X2(u, hi) f8x2m((u), (hi))
#endif

// dot of 16 fp8 (one uint4) with 4 float4 H registers
__device__ __forceinline__ float dot16(uint4 wv, const float4* hh, float s) {
    v2f p;
    p = F8X2(wv.x, 0); s = fmaf(p.x, hh[0].x, s); s = fmaf(p.y, hh[0].y, s);
    p = F8X2(wv.x, 1); s = fmaf(p.x, hh[0].z, s); s = fmaf(p.y, hh[0].w, s);
    p = F8X2(wv.y, 0); s = fmaf(p.x, hh[1].x, s); s = fmaf(p.y, hh[1].y, s);
    p = F8X2(wv.y, 1); s = fmaf(p.x, hh[1].z, s); s = fmaf(p.y, hh[1].w, s);
    p = F8X2(wv.z, 0); s = fmaf(p.x, hh[2].x, s); s = fmaf(p.y, hh[2].y, s);
    p = F8X2(wv.z, 1); s = fmaf(p.x, hh[2].z, s); s = fmaf(p.y, hh[2].w, s);
    p = F8X2(wv.w, 0); s = fmaf(p.x, hh[3].x, s); s = fmaf(p.y, hh[3].y, s);
    p = F8X2(wv.w, 1); s = fmaf(p.x, hh[3].z, s); s = fmaf(p.y, hh[3].w, s);
    return s;
}

// ---------- W fp32 -> fp8 (scaled by 64) into d_ws; also zeroes out[0] ----------
__global__ __launch_bounds__(256) void k_convert_fp8(const float* __restrict__ W,
                                                     uint2* __restrict__ Wf8,
                                                     float* __restrict__ out) {
    if (blockIdx.x == 0 && threadIdx.x == 0) out[0] = 0.0f;
    const size_t nvec = W_ELEMS / 8;                  // 8,192,000 uint2 outputs
    const size_t stride = (size_t)gridDim.x * 256;
    for (size_t i = (size_t)blockIdx.x * 256 + threadIdx.x; i < nvec; i += stride) {
        float4 v0 = reinterpret_cast<const float4*>(W)[2 * i];
        float4 v1 = reinterpret_cast<const float4*>(W)[2 * i + 1];
        uint2 o;
        o.x = pack4(v0.x * SCALE, v0.y * SCALE, v0.z * SCALE, v0.w * SCALE);
        o.y = pack4(v1.x * SCALE, v1.y * SCALE, v1.z * SCALE, v1.w * SCALE);
        Wf8[i] = o;
    }
}

// ---------- monolithic sampled-softmax with fp8 W gather ----------
__global__ __launch_bounds__(256) void k_main_fp8(
    const float* __restrict__ H, const int* __restrict__ labels,
    const unsigned* __restrict__ Wf8, const float* __restrict__ q,
    const int* __restrict__ neg, float* __restrict__ out)
{
    const int n   = blockIdx.x;
    const int tid = threadIdx.x;
    const int sub = tid & 15;   // lane in 16-lane candidate group
    const int grp = tid >> 4;

    __shared__ int   cidx[K_SZ];
    __shared__ float logits[K_SZ];
    __shared__ float red[4];

    for (int i = tid; i < K_SZ; i += 256)
        cidx[i] = (i == 0) ? labels[n] : neg[(size_t)n * KM1 + (i - 1)];

    // Lane sub covers elements [sub*16, sub*16+16) and [256+sub*16, ...):
    const float4* Hr4 = reinterpret_cast<const float4*>(H + (size_t)n * D_SZ);
    float4 ha[4], hb[4];
    #pragma unroll
    for (int j = 0; j < 4; ++j) {
        ha[j] = Hr4[sub * 4 + j];
        hb[j] = Hr4[64 + sub * 4 + j];
    }
    __syncthreads();

    // 2 candidates per iteration -> 4 independent 16B loads in flight
    for (int base = grp; base < K_SZ; base += 32) {
        const int c0 = cidx[base], c1 = cidx[base + 16];
        const uint4* Wr0 = reinterpret_cast<const uint4*>(Wf8 + (size_t)c0 * (D_SZ / 4));
        const uint4* Wr1 = reinterpret_cast<const uint4*>(Wf8 + (size_t)c1 * (D_SZ / 4));
        uint4 a0 = Wr0[sub], a1 = Wr0[16 + sub];   // 16 lanes x 16B = 256B contiguous
        uint4 b0 = Wr1[sub], b1 = Wr1[16 + sub];
        float s0 = dot16(a1, hb, dot16(a0, ha, 0.f));
        float s1 = dot16(b1, hb, dot16(b0, ha, 0.f));
        s0 += __shfl_xor(s0, 1); s1 += __shfl_xor(s1, 1);
        s0 += __shfl_xor(s0, 2); s1 += __shfl_xor(s1, 2);
        s0 += __shfl_xor(s0, 4); s1 += __shfl_xor(s1, 4);
        s0 += __shfl_xor(s0, 8); s1 += __shfl_xor(s1, 8);
        if (sub == 0) { logits[base] = s0 * INV_SCALE; logits[base + 16] = s1 * INV_SCALE; }
    }
    __syncthreads();

    // logsumexp over the 512 logits
    const int wave = tid >> 6;
    float a = logits[tid], b2 = logits[tid + 256];
    float m = fmaxf(a, b2);
    #pragma unroll
    for (int off = 32; off > 0; off >>= 1) m = fmaxf(m, __shfl_xor(m, off));
    if ((tid & 63) == 0) red[wave] = m;
    __syncthreads();
    m = fmaxf(fmaxf(red[0], red[1]), fmaxf(red[2], red[3]));
    __syncthreads();
    float e = __expf(a - m) + __expf(b2 - m);
    #pragma unroll
    for (int off = 32; off > 0; off >>= 1) e += __shfl_xor(e, off);
    if ((tid & 63) == 0) red[wave] = e;
    __syncthreads();
    if (tid == 0) {
        float tot = red[0] + red[1] + red[2] + red[3];
        float lse = m + logf(tot);
        float q0  = fmaxf(q[cidx[0]], 1e-10f);
        atomicAdd(out, (-logits[0] + lse + logf(q0)) * (1.0f / N_ROWS));
    }
}

// ---------------- fallback (round-2 fp32 monolithic kernel) ----------------
__global__ void zero_out_kernel(float* out) { out[0] = 0.0f; }

__global__ __launch_bounds__(256) void sampled_softmax_loss_kernel(
    const float* __restrict__ H, const int* __restrict__ labels,
    const float* __restrict__ W, const float* __restrict__ q,
    const int* __restrict__ neg, float* __restrict__ out)
{
    const int n = blockIdx.x, tid = threadIdx.x;
    const int sub = tid & 15, grp = tid >> 4;
    __shared__ int   cidx[K_SZ];
    __shared__ float logits[K_SZ];
    __shared__ float red[4];
    for (int i = tid; i < K_SZ; i += 256)
        cidx[i] = (i == 0) ? labels[n] : neg[(size_t)n * KM1 + (i - 1)];
    float4 h[8];
    const float4* Hrow = reinterpret_cast<const float4*>(H + (size_t)n * D_SZ);
    #pragma unroll
    for (int ch = 0; ch < 8; ++ch) h[ch] = Hrow[sub + ch * 16];
    __syncthreads();
    for (int base = grp; base < K_SZ; base += 16) {
        const float4* Wrow = reinterpret_cast<const float4*>(W + (size_t)cidx[base] * D_SZ);
        float4 acc = make_float4(0.f, 0.f, 0.f, 0.f);
        #pragma unroll
        for (int ch = 0; ch < 8; ++ch) {
            float4 w = Wrow[sub + ch * 16];
            acc.x = fmaf(w.x, h[ch].x, acc.x); acc.y = fmaf(w.y, h[ch].y, acc.y);
            acc.z = fmaf(w.z, h[ch].z, acc.z); acc.w = fmaf(w.w, h[ch].w, acc.w);
        }
        float s = (acc.x + acc.y) + (acc.z + acc.w);
        s += __shfl_xor(s, 1); s += __shfl_xor(s, 2);
        s += __shfl_xor(s, 4); s += __shfl_xor(s, 8);
        if (sub == 0) logits[base] = s;
    }
    __syncthreads();
    const int wave = tid >> 6;
    float m = -INFINITY;
    for (int i = tid; i < K_SZ; i += 256) m = fmaxf(m, logits[i]);
    #pragma unroll
    for (int off = 32; off > 0; off >>= 1) m = fmaxf(m, __shfl_xor(m, off));
    if ((tid & 63) == 0) red[wave] = m;
    __syncthreads();
    m = fmaxf(fmaxf(red[0], red[1]), fmaxf(red[2], red[3]));
    __syncthreads();
    float s = 0.f;
    for (int i = tid; i < K_SZ; i += 256) s += expf(logits[i] - m);
    #pragma unroll
    for (int off = 32; off > 0; off >>= 1) s += __shfl_xor(s, off);
    if ((tid & 63) == 0) red[wave] = s;
    __syncthreads();
    if (tid == 0) {
        float tot = red[0] + red[1] + red[2] + red[3];
        float lse = m + logf(tot);
        float q0 = fmaxf(q[cidx[0]], 1e-10f);
        atomicAdd(out, (-logits[0] + lse + logf(q0)) * (1.0f / N_ROWS));
    }
}

// ---------------- launch ----------------
extern "C" void kernel_launch(void* const* d_in, const int* in_sizes, int n_in,
                              void* d_out, int out_size, void* d_ws, size_t ws_size,
                              hipStream_t stream) {
    const float* H      = (const float*)d_in[0];
    const int*   labels = (const int*)  d_in[1];
    const float* W      = (const float*)d_in[2];
    const float* q      = (const float*)d_in[3];
    const int*   neg    = (const int*)  d_in[4];
    float* out = (float*)d_out;

    const size_t need_fp8 = W_ELEMS;   // 65,536,000 bytes
    if (ws_size >= need_fp8) {
        unsigned* Wf8 = (unsigned*)d_ws;
        k_convert_fp8<<<2048, 256, 0, stream>>>(W, (uint2*)Wf8, out);
        k_main_fp8   <<<N_ROWS, 256, 0, stream>>>(H, labels, Wf8, q, neg, out);
    } else {
        zero_out_kernel<<<1, 1, 0, stream>>>(out);
        sampled_softmax_loss_kernel<<<N_ROWS, 256, 0, stream>>>(H, labels, W, q, neg, out);
    }
}